// Round 6
// baseline (452.370 us; speedup 1.0000x reference)
//
#include <hip/hip_runtime.h>
#include <hip/hip_bf16.h>
#include <stdint.h>
#include <math.h>

typedef __attribute__((ext_vector_type(8))) short short8;
typedef __attribute__((ext_vector_type(4))) float f32x4;

#define H_DIM 1024
#define T_SEQ 4096
#define BM 128
#define BN 128
#define BK 32
#define CHUNK 16   // rows per wave in the ring attention kernel

static __device__ __forceinline__ float bf2f(unsigned short u) {
  union { unsigned int i; float f; } c;
  c.i = ((unsigned int)u) << 16;
  return c.f;
}

static __device__ __forceinline__ unsigned short f2bf(float f) {
  __hip_bfloat16 h = __float2bfloat16(f);  // RNE
  unsigned short u;
  __builtin_memcpy(&u, &h, 2);
  return u;
}

static __device__ __forceinline__ void gload16(const void* g, void* l) {
  __builtin_amdgcn_global_load_lds(
      (const __attribute__((address_space(1))) void*)g,
      (__attribute__((address_space(3))) void*)l,
      16, 0, 0);
}

// ---------------------------------------------------------------------------
// f32 -> bf16 conversion, 8 elements/thread/iter (float4 x2 in, short8 out).
// ---------------------------------------------------------------------------
__global__ __launch_bounds__(256) void cvt_kernel(
    const float* __restrict__ in, __hip_bfloat16* __restrict__ out, int n8)
{
  int i = blockIdx.x * blockDim.x + threadIdx.x;
  const int stride = gridDim.x * blockDim.x;
  for (; i < n8; i += stride) {
    const float4* p = (const float4*)in + (size_t)i * 2;
    float4 a = p[0], b = p[1];
    short8 o;
    o[0] = (short)f2bf(a.x); o[1] = (short)f2bf(a.y);
    o[2] = (short)f2bf(a.z); o[3] = (short)f2bf(a.w);
    o[4] = (short)f2bf(b.x); o[5] = (short)f2bf(b.y);
    o[6] = (short)f2bf(b.z); o[7] = (short)f2bf(b.w);
    ((short8*)out)[i] = o;
  }
}

// Same, for the three weight matrices in one launch (blockIdx.y selects).
__global__ __launch_bounds__(256) void cvt3_kernel(
    const float* __restrict__ i0, const float* __restrict__ i1,
    const float* __restrict__ i2,
    __hip_bfloat16* __restrict__ o0, __hip_bfloat16* __restrict__ o1,
    __hip_bfloat16* __restrict__ o2, int n8)
{
  const float* in = (blockIdx.y == 0) ? i0 : ((blockIdx.y == 1) ? i1 : i2);
  __hip_bfloat16* out = (blockIdx.y == 0) ? o0 : ((blockIdx.y == 1) ? o1 : o2);
  int i = blockIdx.x * blockDim.x + threadIdx.x;
  const int stride = gridDim.x * blockDim.x;
  for (; i < n8; i += stride) {
    const float4* p = (const float4*)in + (size_t)i * 2;
    float4 a = p[0], b = p[1];
    short8 o;
    o[0] = (short)f2bf(a.x); o[1] = (short)f2bf(a.y);
    o[2] = (short)f2bf(a.z); o[3] = (short)f2bf(a.w);
    o[4] = (short)f2bf(b.x); o[5] = (short)f2bf(b.y);
    o[6] = (short)f2bf(b.z); o[7] = (short)f2bf(b.w);
    ((short8*)out)[i] = o;
  }
}

// ---------------------------------------------------------------------------
// Fused QKV projection: out = X @ W^T + b for W in {Wq, Wk, Wv} (bf16 copies).
// m97 structure: 128x128 tile, BK=32, 4 waves (2x2), 16x16x32 bf16 MFMA,
// global_load_lds width-16 staging, 2 barriers per K-step. Bias is f32.
// (Measured r4: 137 us, MfmaUtil 33% — at the m97-structure ceiling.)
// ---------------------------------------------------------------------------
__global__ __launch_bounds__(256) void qkv_gemm_kernel(
    const __hip_bfloat16* __restrict__ X,
    const __hip_bfloat16* __restrict__ Wq,
    const __hip_bfloat16* __restrict__ Wk,
    const __hip_bfloat16* __restrict__ Wv,
    const float* __restrict__ bq,
    const float* __restrict__ bk,
    const float* __restrict__ bv,
    __hip_bfloat16* __restrict__ Qo,
    __hip_bfloat16* __restrict__ Ko,
    __hip_bfloat16* __restrict__ Vo,
    int M)
{
  __shared__ __hip_bfloat16 sA[BM * BK];   // 8 KiB
  __shared__ __hip_bfloat16 sB[BN * BK];   // 8 KiB

  const int m0 = blockIdx.x * BM;
  const int ytile = blockIdx.y;           // 0..23
  const int which = ytile >> 3;           // 0:Q 1:K 2:V
  const int n_local = (ytile & 7) * BN;   // 0..896 within the selected W

  const __hip_bfloat16* Wsel = (which == 0) ? Wq : ((which == 1) ? Wk : Wv);
  const float* Bsel          = (which == 0) ? bq : ((which == 1) ? bk : bv);
  __hip_bfloat16* Osel       = (which == 0) ? Qo : ((which == 1) ? Ko : Vo);

  const int tid  = threadIdx.x;
  const int lane = tid & 63;
  const int wv   = tid >> 6;        // wave 0..3
  const int wm   = (wv >> 1) * 64;  // wave tile row origin
  const int wn   = (wv & 1) * 64;   // wave tile col origin

  f32x4 acc[4][4];
  #pragma unroll
  for (int i = 0; i < 4; ++i)
    #pragma unroll
    for (int j = 0; j < 4; ++j)
      acc[i][j] = (f32x4){0.f, 0.f, 0.f, 0.f};

  const int ar = wm + (lane & 15);  // A fragment row within tile
  const int br = wn + (lane & 15);  // B fragment row (= output col) within tile
  const int kq = lane >> 4;         // k-quarter 0..3 (8 bf16 each)

  const int nkt = H_DIM / BK;       // 32 K-steps

  for (int kt = 0; kt < nkt; ++kt) {
    const int k0 = kt * BK;
    #pragma unroll
    for (int i = 0; i < 2; ++i) {
      int idx = i * 256 + tid;
      int row = idx >> 2;
      int ck  = (idx & 3) * 8;
      gload16(X    + (size_t)(m0 + row)      * H_DIM + k0 + ck, (char*)sA + idx * 16);
      gload16(Wsel + (size_t)(n_local + row) * H_DIM + k0 + ck, (char*)sB + idx * 16);
    }
    __syncthreads();

    const short8* pA = (const short8*)sA;
    const short8* pB = (const short8*)sB;
    short8 afrag[4], bfrag[4];
    #pragma unroll
    for (int mi = 0; mi < 4; ++mi)
      afrag[mi] = pA[(ar + mi * 16) * 4 + kq];
    #pragma unroll
    for (int ni = 0; ni < 4; ++ni)
      bfrag[ni] = pB[(br + ni * 16) * 4 + kq];

    #pragma unroll
    for (int mi = 0; mi < 4; ++mi)
      #pragma unroll
      for (int ni = 0; ni < 4; ++ni)
        acc[mi][ni] = __builtin_amdgcn_mfma_f32_16x16x32_bf16(
            afrag[mi], bfrag[ni], acc[mi][ni], 0, 0, 0);

    __syncthreads();
  }

  // Epilogue: f32 bias add + bf16 store.
  // C/D layout (verified m89/m91): col = lane&15, row = (lane>>4)*4 + reg.
  #pragma unroll
  for (int ni = 0; ni < 4; ++ni) {
    const int col = n_local + wn + ni * 16 + (lane & 15);
    const float bias = Bsel[col];
    #pragma unroll
    for (int mi = 0; mi < 4; ++mi) {
      const int rowbase = m0 + wm + mi * 16 + (lane >> 4) * 4;
      #pragma unroll
      for (int r = 0; r < 4; ++r) {
        float v = acc[mi][ni][r] + bias;
        Osel[(size_t)(rowbase + r) * H_DIM + col] = __float2bfloat16(v);
      }
    }
  }
}

// ---------------------------------------------------------------------------
// Ring-buffer windowed attention. One wave per CHUNK=16 consecutive rows.
// 9-slot K/V ring in registers (bf16): each K/V row loaded ONCE from memory
// (vs 9x in the per-row version — r4 measured that at ~140 us, pure traffic).
// Slot of key row r' for chunk base row0: s = (r' - row0 + 8) % 9; all slot
// indices are compile-time constants after full unroll (no scratch, rule #20).
// ---------------------------------------------------------------------------
static __device__ __forceinline__ float dot16(const float* q,
                                              const short8& a, const short8& b) {
  float d = 0.f;
  #pragma unroll
  for (int e = 0; e < 8; ++e) d += q[e] * bf2f((unsigned short)a[e]);
  #pragma unroll
  for (int e = 0; e < 8; ++e) d += q[8 + e] * bf2f((unsigned short)b[e]);
  return d;
}

template<bool EDGE>
static __device__ __forceinline__ void attn_chunk(
    const __hip_bfloat16* __restrict__ Q,
    const __hip_bfloat16* __restrict__ Km,
    const __hip_bfloat16* __restrict__ V,
    float* __restrict__ Out,
    int row0, int lane)
{
  const float scale = 0.03125f;  // 1/sqrt(1024)
  const size_t lanoff = (size_t)lane * 16;

  short8 kr[9][2];
  short8 vr[9][2];

  // Preload key/value rows row0-8 .. row0-1 into slots 0..7.
  // EDGE (row0 at batch start): those rows are invalid -> zero-fill (keeps
  // the V accumulation NaN-free; scores are masked to -inf below).
  #pragma unroll
  for (int j = 0; j < 8; ++j) {
    if (EDGE) {
      short8 z = {0, 0, 0, 0, 0, 0, 0, 0};
      kr[j][0] = z; kr[j][1] = z;
      vr[j][0] = z; vr[j][1] = z;
    } else {
      const size_t rb = (size_t)(row0 - 8 + j) * H_DIM + lanoff;
      const short8* kp = (const short8*)(Km + rb);
      kr[j][0] = kp[0]; kr[j][1] = kp[1];
      const short8* vp = (const short8*)(V + rb);
      vr[j][0] = vp[0]; vr[j][1] = vp[1];
    }
  }

  #pragma unroll
  for (int i = 0; i < CHUNK; ++i) {
    const size_t rb = (size_t)(row0 + i) * H_DIM + lanoff;

    // Load current row's K/V into the ring (always in-batch).
    {
      const int snew = (i + 8) % 9;
      const short8* kp = (const short8*)(Km + rb);
      kr[snew][0] = kp[0]; kr[snew][1] = kp[1];
      const short8* vp = (const short8*)(V + rb);
      vr[snew][0] = vp[0]; vr[snew][1] = vp[1];
    }

    // Load Q row, convert to f32.
    float q[16];
    {
      const short8* p = (const short8*)(Q + rb);
      short8 a = p[0], b = p[1];
      #pragma unroll
      for (int e = 0; e < 8; ++e) {
        q[e]     = bf2f((unsigned short)a[e]);
        q[8 + e] = bf2f((unsigned short)b[e]);
      }
    }

    // Scores: window position j corresponds to key row row0+i-8+j (slot (i+j)%9).
    float sc[9];
    #pragma unroll
    for (int j = 0; j < 9; ++j) {
      const int s = (i + j) % 9;
      if (EDGE && (i - 8 + j < 0)) {
        sc[j] = -INFINITY;
      } else {
        float d = dot16(q, kr[s][0], kr[s][1]);
        #pragma unroll
        for (int off = 32; off >= 1; off >>= 1) d += __shfl_xor(d, off, 64);
        sc[j] = d * scale;
      }
    }

    // Softmax over 9 slots (j=8 — the diagonal — is always valid, so m finite).
    float m = sc[0];
    #pragma unroll
    for (int j = 1; j < 9; ++j) m = fmaxf(m, sc[j]);
    float l = 0.f;
    #pragma unroll
    for (int j = 0; j < 9; ++j) { sc[j] = __expf(sc[j] - m); l += sc[j]; }
    const float inv = 1.f / l;

    // Weighted V sum. Invalid slots have weight exactly 0 and zero-filled vr.
    float o[16];
    #pragma unroll
    for (int e = 0; e < 16; ++e) o[e] = 0.f;
    #pragma unroll
    for (int j = 0; j < 9; ++j) {
      const int s = (i + j) % 9;
      const float aw = sc[j] * inv;
      #pragma unroll
      for (int e = 0; e < 8; ++e) {
        o[e]     += aw * bf2f((unsigned short)vr[s][0][e]);
        o[8 + e] += aw * bf2f((unsigned short)vr[s][1][e]);
      }
    }

    float4* op = (float4*)(Out + rb);
    op[0] = (float4){o[0],  o[1],  o[2],  o[3]};
    op[1] = (float4){o[4],  o[5],  o[6],  o[7]};
    op[2] = (float4){o[8],  o[9],  o[10], o[11]};
    op[3] = (float4){o[12], o[13], o[14], o[15]};
  }
}

__global__ __launch_bounds__(256, 1) void local_attn_ring_kernel(
    const __hip_bfloat16* __restrict__ Q,
    const __hip_bfloat16* __restrict__ Km,
    const __hip_bfloat16* __restrict__ V,
    const int* __restrict__ winp,
    float* __restrict__ Out,
    int M)
{
  const int wave = (int)((blockIdx.x * blockDim.x + threadIdx.x) >> 6);
  const int lane = threadIdx.x & 63;
  const int row0 = wave * CHUNK;
  if (row0 >= M) return;
  const int t0 = row0 & (T_SEQ - 1);
  const int Wn = *winp;

  if (Wn == 8) {
    if (t0 == 0) attn_chunk<true >(Q, Km, V, Out, row0, lane);
    else         attn_chunk<false>(Q, Km, V, Out, row0, lane);
    return;
  }

  // Generic fallback (any window size): per-row online softmax.
  const float scale = 0.03125f;
  for (int i = 0; i < CHUNK; ++i) {
    const int row = row0 + i;
    const int t = row & (T_SEQ - 1);
    const size_t rb = (size_t)row * H_DIM + (size_t)lane * 16;

    float q[16];
    {
      const short8* p = (const short8*)(Q + rb);
      short8 a = p[0], b = p[1];
      #pragma unroll
      for (int e = 0; e < 8; ++e) {
        q[e]     = bf2f((unsigned short)a[e]);
        q[8 + e] = bf2f((unsigned short)b[e]);
      }
    }

    float m = -INFINITY, l = 0.f;
    float o[16];
    #pragma unroll
    for (int e = 0; e < 16; ++e) o[e] = 0.f;
    for (int w = 0; w <= Wn; ++w) {
      const int dt = Wn - w;
      if (t - dt < 0) continue;
      const size_t kb = rb - (size_t)dt * H_DIM;
      const short8* kp = (const short8*)(Km + kb);
      short8 ka = kp[0], kb8 = kp[1];
      float d = dot16(q, ka, kb8);
      #pragma unroll
      for (int off = 32; off >= 1; off >>= 1) d += __shfl_xor(d, off, 64);
      const float s = d * scale;
      const float mn = fmaxf(m, s);
      const float corr = (m == -INFINITY) ? 0.f : __expf(m - mn);
      const float p = __expf(s - mn);
      l = l * corr + p;
      const short8* vp = (const short8*)(V + kb);
      short8 va = vp[0], vb = vp[1];
      #pragma unroll
      for (int e = 0; e < 8; ++e) {
        o[e]     = o[e]     * corr + p * bf2f((unsigned short)va[e]);
        o[8 + e] = o[8 + e] * corr + p * bf2f((unsigned short)vb[e]);
      }
      m = mn;
    }
    const float inv = 1.f / l;
    float4* op = (float4*)(Out + rb);
    op[0] = (float4){o[0]  * inv, o[1]  * inv, o[2]  * inv, o[3]  * inv};
    op[1] = (float4){o[4]  * inv, o[5]  * inv, o[6]  * inv, o[7]  * inv};
    op[2] = (float4){o[8]  * inv, o[9]  * inv, o[10] * inv, o[11] * inv};
    op[3] = (float4){o[12] * inv, o[13] * inv, o[14] * inv, o[15] * inv};
  }
}

extern "C" void kernel_launch(void* const* d_in, const int* in_sizes, int n_in,
                              void* d_out, int out_size, void* d_ws, size_t ws_size,
                              hipStream_t stream) {
  const float* X  = (const float*)d_in[0];
  const float* Wq = (const float*)d_in[1];
  const float* bq = (const float*)d_in[2];
  const float* Wk = (const float*)d_in[3];
  const float* bk = (const float*)d_in[4];
  const float* Wv = (const float*)d_in[5];
  const float* bv = (const float*)d_in[6];
  const int* winp = (const int*)d_in[7];

  const int M = in_sizes[0] / H_DIM;  // B*T = 16384
  const size_t MH = (size_t)M * H_DIM;
  const size_t HH = (size_t)H_DIM * H_DIM;

  // Workspace (bf16): Xb | Wqb | Wkb | Wvb | Qb | Kb | Vb  (~134 MiB)
  __hip_bfloat16* Xb  = (__hip_bfloat16*)d_ws;
  __hip_bfloat16* Wqb = Xb  + MH;
  __hip_bfloat16* Wkb = Wqb + HH;
  __hip_bfloat16* Wvb = Wkb + HH;
  __hip_bfloat16* Qb  = Wvb + HH;
  __hip_bfloat16* Kb  = Qb  + MH;
  __hip_bfloat16* Vb  = Kb  + MH;
  float* Out = (float*)d_out;

  // 1) f32 -> bf16 conversions.
  cvt_kernel<<<2048, 256, 0, stream>>>(X, Xb, (int)(MH / 8));
  cvt3_kernel<<<dim3(512, 3), 256, 0, stream>>>(Wq, Wk, Wv, Wqb, Wkb, Wvb,
                                                (int)(HH / 8));

  // 2) Fused QKV GEMM.
  dim3 g1(M / BM, 3 * (H_DIM / BN));  // 128 x 24
  qkv_gemm_kernel<<<g1, 256, 0, stream>>>(Xb, Wqb, Wkb, Wvb, bq, bk, bv,
                                          Qb, Kb, Vb, M);

  // 3) Ring-buffer windowed attention (f32 out).
  const int waves = M / CHUNK;            // 1024
  const int blocks = (waves + 3) / 4;     // 4 waves per 256-thread block
  local_attn_ring_kernel<<<blocks, 256, 0, stream>>>(Qb, Kb, Vb, winp, Out, M);
}

// Round 8
// 292.237 us; speedup vs baseline: 1.5480x; 1.5480x over previous
//
#include <hip/hip_runtime.h>
#include <hip/hip_bf16.h>
#include <stdint.h>
#include <math.h>

typedef __attribute__((ext_vector_type(8))) short short8;
typedef __attribute__((ext_vector_type(4))) float f32x4;

#define H_DIM 1024
#define T_SEQ 4096

static __device__ __forceinline__ float bf2f(unsigned short u) {
  union { unsigned int i; float f; } c;
  c.i = ((unsigned int)u) << 16;
  return c.f;
}

static __device__ __forceinline__ unsigned short f2bf(float f) {
  __hip_bfloat16 h = __float2bfloat16(f);  // RNE
  unsigned short u;
  __builtin_memcpy(&u, &h, 2);
  return u;
}

static __device__ __forceinline__ void gload16(const void* g, void* l) {
  __builtin_amdgcn_global_load_lds(
      (const __attribute__((address_space(1))) void*)g,
      (__attribute__((address_space(3))) void*)l,
      16, 0, 0);
}

#define FENCE asm volatile("" ::: "memory")
#define BAR   __builtin_amdgcn_s_barrier()
#define LGKM0 asm volatile("s_waitcnt lgkmcnt(0)" ::: "memory")

// ---------------------------------------------------------------------------
// f32 -> bf16 conversion kernels (unchanged from r4; ~29 us total).
// ---------------------------------------------------------------------------
__global__ __launch_bounds__(256) void cvt_kernel(
    const float* __restrict__ in, __hip_bfloat16* __restrict__ out, int n8)
{
  int i = blockIdx.x * blockDim.x + threadIdx.x;
  const int stride = gridDim.x * blockDim.x;
  for (; i < n8; i += stride) {
    const float4* p = (const float4*)in + (size_t)i * 2;
    float4 a = p[0], b = p[1];
    short8 o;
    o[0] = (short)f2bf(a.x); o[1] = (short)f2bf(a.y);
    o[2] = (short)f2bf(a.z); o[3] = (short)f2bf(a.w);
    o[4] = (short)f2bf(b.x); o[5] = (short)f2bf(b.y);
    o[6] = (short)f2bf(b.z); o[7] = (short)f2bf(b.w);
    ((short8*)out)[i] = o;
  }
}

__global__ __launch_bounds__(256) void cvt3_kernel(
    const float* __restrict__ i0, const float* __restrict__ i1,
    const float* __restrict__ i2,
    __hip_bfloat16* __restrict__ o0, __hip_bfloat16* __restrict__ o1,
    __hip_bfloat16* __restrict__ o2, int n8)
{
  const float* in = (blockIdx.y == 0) ? i0 : ((blockIdx.y == 1) ? i1 : i2);
  __hip_bfloat16* out = (blockIdx.y == 0) ? o0 : ((blockIdx.y == 1) ? o1 : o2);
  int i = blockIdx.x * blockDim.x + threadIdx.x;
  const int stride = gridDim.x * blockDim.x;
  for (; i < n8; i += stride) {
    const float4* p = (const float4*)in + (size_t)i * 2;
    float4 a = p[0], b = p[1];
    short8 o;
    o[0] = (short)f2bf(a.x); o[1] = (short)f2bf(a.y);
    o[2] = (short)f2bf(a.z); o[3] = (short)f2bf(a.w);
    o[4] = (short)f2bf(b.x); o[5] = (short)f2bf(b.y);
    o[6] = (short)f2bf(b.z); o[7] = (short)f2bf(b.w);
    ((short8*)out)[i] = o;
  }
}

// ---------------------------------------------------------------------------
// 8-phase 256x256 fused QKV GEMM (T2 swizzle + T3/T4 counted-vmcnt + T5).
// BM=BN=256, BK=64, 8 waves (2Mx4N), 512 threads, 128 KiB LDS double buffer.
// K-tile t: 4 phases; reads: ph0 A[m0-3]+B[n0-1] (12), ph1 B[n2-3] (4),
// ph2 A[m4-7] (8), ph3 none. Stages (1 half = 128x64 bf16 = 16KB, 2 gloads
// per thread): ph0 A0[t+1]->buf^1, ph1 A1[t+1]->buf^1, ph2 B0[t+2]->buf,
// ph3 B1[t+2]->buf. Each slot staged only after its last reader's barrier
// (A halves read ph0+ph2 of previous tile in the OTHER buffer; B halves of
// THIS buffer read ph0+ph1). vmcnt(4) at tile end ensures next tile's halves
// landed (2 B-halves = 4 loads still in flight). Never drains to 0 mid-loop.
// LDS swizzle: byte ^= ((byte>>7)&7)<<4 (involution; permutes 16B slots
// within each 128B row by row index) applied on ds_read addr AND inverse-
// applied on the per-lane GLOBAL source while gload_lds dest stays linear
// (rule #21 both-sides-or-neither).
// ---------------------------------------------------------------------------
#define GNT 16          // K tiles = 1024/64

static __device__ __forceinline__ void stage_half(
    const __hip_bfloat16* __restrict__ G, int grow0, int k0, char* dstHalf,
    int tid)
{
  const int w = tid >> 6, l = tid & 63;
  #pragma unroll
  for (int r = 0; r < 2; ++r) {
    const int D = (r * 8 + w) * 1024 + l * 16;     // linear LDS byte in half
    const int L = D ^ (((D >> 7) & 7) << 4);       // inverse-swizzled source
    const int row = L >> 7;                        // 0..127
    const int cb  = L & 127;                       // byte within 128B row
    const char* src = (const char*)G + (size_t)(grow0 + row) * (H_DIM * 2)
                      + k0 * 2 + cb;
    gload16(src, dstHalf + D);
  }
}

static __device__ __forceinline__ short8 lds_frag(const char* half, int row,
                                                  int ksub, int kq)
{
  int a = row * 128 + ksub * 64 + kq * 16;
  a ^= ((row & 7) << 4);   // same involution ((a>>7)&7 == row&7)
  return *(const short8*)(half + a);
}

__global__ __launch_bounds__(512, 1) void qkv_gemm8_kernel(
    const __hip_bfloat16* __restrict__ X,
    const __hip_bfloat16* __restrict__ Wq,
    const __hip_bfloat16* __restrict__ Wk,
    const __hip_bfloat16* __restrict__ Wv,
    const float* __restrict__ bq,
    const float* __restrict__ bk,
    const float* __restrict__ bv,
    __hip_bfloat16* __restrict__ Qo,
    __hip_bfloat16* __restrict__ Ko,
    __hip_bfloat16* __restrict__ Vo,
    int M)
{
  __shared__ char lds[131072];   // 2 bufs x (A 32KB + B 32KB)

  const int m0 = blockIdx.x * 256;
  const int ytile = blockIdx.y;          // 0..11
  const int which = ytile >> 2;          // 0:Q 1:K 2:V
  const int nb = (ytile & 3) * 256;      // col base within selected W

  const __hip_bfloat16* Wsel = (which == 0) ? Wq : ((which == 1) ? Wk : Wv);
  const float* Bsel          = (which == 0) ? bq : ((which == 1) ? bk : bv);
  __hip_bfloat16* Osel       = (which == 0) ? Qo : ((which == 1) ? Ko : Vo);

  const int tid  = threadIdx.x;
  const int lane = tid & 63;
  const int wid  = tid >> 6;       // 0..7
  const int wr   = wid >> 2;       // 0..1  (M dim, 128 rows each)
  const int wc   = wid & 3;        // 0..3  (N dim, 64 cols each)
  const int lrow = lane & 15;
  const int kq   = lane >> 4;

  // LDS region helpers: buf b in [b*65536, +65536): A halves at 0,16K; B at 32K,48K.
  #define AHALF(b, h) (lds + (b) * 65536 + (h) * 16384)
  #define BHALF(b, h) (lds + (b) * 65536 + 32768 + (h) * 16384)

  f32x4 acc[8][4];
  #pragma unroll
  for (int i = 0; i < 8; ++i)
    #pragma unroll
    for (int j = 0; j < 4; ++j)
      acc[i][j] = (f32x4){0.f, 0.f, 0.f, 0.f};

  // ---- Prologue: stage tile0 fully + tile1's B halves; vmcnt(4); barrier.
  stage_half(Wsel, nb +   0, 0,  BHALF(0, 0), tid);
  stage_half(Wsel, nb + 128, 0,  BHALF(0, 1), tid);
  stage_half(X,    m0 +   0, 0,  AHALF(0, 0), tid);
  stage_half(X,    m0 + 128, 0,  AHALF(0, 1), tid);
  stage_half(Wsel, nb +   0, 64, BHALF(1, 0), tid);
  stage_half(Wsel, nb + 128, 64, BHALF(1, 1), tid);
  asm volatile("s_waitcnt vmcnt(4)" ::: "memory");
  BAR;

  short8 aF[4][2];
  short8 bF[4][2];

  for (int t = 0; t < GNT; ++t) {
    const int cur = t & 1, nxt = cur ^ 1;
    const char* myA = AHALF(cur, wr);
    const char* myB = BHALF(cur, wc >> 1);
    const int rB0 = (wc & 1) * 64;

    // ---------------- phase 0: read A[m0-3], B[n0-1]; stage A0[t+1]
    #pragma unroll
    for (int mi = 0; mi < 4; ++mi)
      #pragma unroll
      for (int ks = 0; ks < 2; ++ks)
        aF[mi][ks] = lds_frag(myA, mi * 16 + lrow, ks, kq);
    #pragma unroll
    for (int ni = 0; ni < 2; ++ni)
      #pragma unroll
      for (int ks = 0; ks < 2; ++ks)
        bF[ni][ks] = lds_frag(myB, rB0 + ni * 16 + lrow, ks, kq);
    if (t + 1 < GNT) stage_half(X, m0 + 0, (t + 1) * 64, AHALF(nxt, 0), tid);
    FENCE; BAR; LGKM0; __builtin_amdgcn_sched_barrier(0);
    __builtin_amdgcn_s_setprio(1);
    #pragma unroll
    for (int mi = 0; mi < 4; ++mi)
      #pragma unroll
      for (int ni = 0; ni < 2; ++ni)
        #pragma unroll
        for (int ks = 0; ks < 2; ++ks)
          acc[mi][ni] = __builtin_amdgcn_mfma_f32_16x16x32_bf16(
              aF[mi][ks], bF[ni][ks], acc[mi][ni], 0, 0, 0);
    __builtin_amdgcn_s_setprio(0);
    FENCE; BAR;

    // ---------------- phase 1: read B[n2-3]; stage A1[t+1]
    #pragma unroll
    for (int ni = 2; ni < 4; ++ni)
      #pragma unroll
      for (int ks = 0; ks < 2; ++ks)
        bF[ni][ks] = lds_frag(myB, rB0 + ni * 16 + lrow, ks, kq);
    if (t + 1 < GNT) stage_half(X, m0 + 128, (t + 1) * 64, AHALF(nxt, 1), tid);
    FENCE; BAR; LGKM0; __builtin_amdgcn_sched_barrier(0);
    __builtin_amdgcn_s_setprio(1);
    #pragma unroll
    for (int mi = 0; mi < 4; ++mi)
      #pragma unroll
      for (int ni = 2; ni < 4; ++ni)
        #pragma unroll
        for (int ks = 0; ks < 2; ++ks)
          acc[mi][ni] = __builtin_amdgcn_mfma_f32_16x16x32_bf16(
              aF[mi][ks], bF[ni][ks], acc[mi][ni], 0, 0, 0);
    __builtin_amdgcn_s_setprio(0);
    FENCE; BAR;

    // ---------------- phase 2: read A[m4-7]; stage B0[t+2]
    #pragma unroll
    for (int mi = 0; mi < 4; ++mi)
      #pragma unroll
      for (int ks = 0; ks < 2; ++ks)
        aF[mi][ks] = lds_frag(myA, (mi + 4) * 16 + lrow, ks, kq);
    if (t + 2 < GNT) stage_half(Wsel, nb + 0, (t + 2) * 64, BHALF(cur, 0), tid);
    FENCE; BAR; LGKM0; __builtin_amdgcn_sched_barrier(0);
    __builtin_amdgcn_s_setprio(1);
    #pragma unroll
    for (int mi = 0; mi < 4; ++mi)
      #pragma unroll
      for (int ni = 0; ni < 2; ++ni)
        #pragma unroll
        for (int ks = 0; ks < 2; ++ks)
          acc[mi + 4][ni] = __builtin_amdgcn_mfma_f32_16x16x32_bf16(
              aF[mi][ks], bF[ni][ks], acc[mi + 4][ni], 0, 0, 0);
    __builtin_amdgcn_s_setprio(0);
    FENCE; BAR;

    // ---------------- phase 3: stage B1[t+2]; MFMA from regs; tile-end vmcnt
    if (t + 2 < GNT) stage_half(Wsel, nb + 128, (t + 2) * 64, BHALF(cur, 1), tid);
    FENCE;
    __builtin_amdgcn_s_setprio(1);
    #pragma unroll
    for (int mi = 0; mi < 4; ++mi)
      #pragma unroll
      for (int ni = 2; ni < 4; ++ni)
        #pragma unroll
        for (int ks = 0; ks < 2; ++ks)
          acc[mi + 4][ni] = __builtin_amdgcn_mfma_f32_16x16x32_bf16(
              aF[mi][ks], bF[ni][ks], acc[mi + 4][ni], 0, 0, 0);
    __builtin_amdgcn_s_setprio(0);
    // End-of-tile: ensure tile t+1's 4 halves have landed before anyone reads.
    if (t + 2 < GNT) { asm volatile("s_waitcnt vmcnt(4)" ::: "memory"); }
    else             { asm volatile("s_waitcnt vmcnt(0)" ::: "memory"); }
    FENCE; BAR;
  }

  // ---- Epilogue: bias + bf16 store. C/D: col=lane&15, row=(lane>>4)*4+reg.
  #pragma unroll
  for (int ni = 0; ni < 4; ++ni) {
    const int col = nb + wc * 64 + ni * 16 + lrow;
    const float bias = Bsel[col];
    #pragma unroll
    for (int mi = 0; mi < 8; ++mi) {
      const int rowbase = m0 + wr * 128 + mi * 16 + kq * 4;
      #pragma unroll
      for (int r = 0; r < 4; ++r) {
        float v = acc[mi][ni][r] + bias;
        Osel[(size_t)(rowbase + r) * H_DIM + col] = __float2bfloat16(v);
      }
    }
  }
  #undef AHALF
  #undef BHALF
}

// ---------------------------------------------------------------------------
// Windowed causal attention (r4-verified version, ~64 us). One wave per row.
// ---------------------------------------------------------------------------
__global__ __launch_bounds__(256) void local_attn_kernel(
    const __hip_bfloat16* __restrict__ Q,
    const __hip_bfloat16* __restrict__ Km,
    const __hip_bfloat16* __restrict__ V,
    const int* __restrict__ winp,
    float* __restrict__ Out,
    int M)
{
  const int row = (int)((blockIdx.x * blockDim.x + threadIdx.x) >> 6);
  if (row >= M) return;
  const int lane = threadIdx.x & 63;
  const int t = row & (T_SEQ - 1);
  const int Wn = *winp;  // 8 for this problem
  const float scale = 0.03125f;  // 1/sqrt(1024)

  const size_t base = (size_t)row * H_DIM + (size_t)lane * 16;

  float q[16];
  {
    const short8* p = (const short8*)(Q + base);
    short8 a = p[0], b = p[1];
    #pragma unroll
    for (int j = 0; j < 8; ++j) {
      q[j]     = bf2f((unsigned short)a[j]);
      q[8 + j] = bf2f((unsigned short)b[j]);
    }
  }

  if (Wn == 8) {
    float sc[9];
    #pragma unroll
    for (int w = 0; w < 9; ++w) {
      const int dt = 8 - w;
      float s = -INFINITY;
      if (t - dt >= 0) {
        const short8* kp = (const short8*)(Km + base - (size_t)dt * H_DIM);
        short8 ka = kp[0], kb = kp[1];
        float d = 0.f;
        #pragma unroll
        for (int j = 0; j < 8; ++j) {
          d += q[j]     * bf2f((unsigned short)ka[j]);
          d += q[8 + j] * bf2f((unsigned short)kb[j]);
        }
        #pragma unroll
        for (int off = 32; off >= 1; off >>= 1) d += __shfl_xor(d, off, 64);
        s = d * scale;
      }
      sc[w] = s;
    }
    float m = sc[0];
    #pragma unroll
    for (int w = 1; w < 9; ++w) m = fmaxf(m, sc[w]);
    float l = 0.f;
    #pragma unroll
    for (int w = 0; w < 9; ++w) { sc[w] = __expf(sc[w] - m); l += sc[w]; }
    const float inv = 1.f / l;

    float o[16];
    #pragma unroll
    for (int j = 0; j < 16; ++j) o[j] = 0.f;
    #pragma unroll
    for (int w = 0; w < 9; ++w) {
      const int dt = 8 - w;
      if (t - dt >= 0) {
        const short8* vp = (const short8*)(V + base - (size_t)dt * H_DIM);
        short8 va = vp[0], vb = vp[1];
        const float aw = sc[w] * inv;
        #pragma unroll
        for (int j = 0; j < 8; ++j) {
          o[j]     += aw * bf2f((unsigned short)va[j]);
          o[8 + j] += aw * bf2f((unsigned short)vb[j]);
        }
      }
    }

    float4* op = (float4*)(Out + base);
    op[0] = (float4){o[0],  o[1],  o[2],  o[3]};
    op[1] = (float4){o[4],  o[5],  o[6],  o[7]};
    op[2] = (float4){o[8],  o[9],  o[10], o[11]};
    op[3] = (float4){o[12], o[13], o[14], o[15]};
  } else {
    float m = -INFINITY, l = 0.f;
    float o[16];
    #pragma unroll
    for (int j = 0; j < 16; ++j) o[j] = 0.f;
    for (int w = 0; w <= Wn; ++w) {
      const int dt = Wn - w;
      if (t - dt < 0) continue;
      const short8* kp = (const short8*)(Km + base - (size_t)dt * H_DIM);
      short8 ka = kp[0], kb = kp[1];
      float d = 0.f;
      #pragma unroll
      for (int j = 0; j < 8; ++j) {
        d += q[j]     * bf2f((unsigned short)ka[j]);
        d += q[8 + j] * bf2f((unsigned short)kb[j]);
      }
      #pragma unroll
      for (int off = 32; off >= 1; off >>= 1) d += __shfl_xor(d, off, 64);
      const float s = d * scale;
      const float mn = fmaxf(m, s);
      const float corr = (m == -INFINITY) ? 0.f : __expf(m - mn);
      const float p = __expf(s - mn);
      l = l * corr + p;
      const short8* vp = (const short8*)(V + base - (size_t)dt * H_DIM);
      short8 va = vp[0], vb = vp[1];
      #pragma unroll
      for (int j = 0; j < 8; ++j) {
        o[j]     = o[j]     * corr + p * bf2f((unsigned short)va[j]);
        o[8 + j] = o[8 + j] * corr + p * bf2f((unsigned short)vb[j]);
      }
      m = mn;
    }
    const float inv = 1.f / l;
    float4* op = (float4*)(Out + base);
    op[0] = (float4){o[0]  * inv, o[1]  * inv, o[2]  * inv, o[3]  * inv};
    op[1] = (float4){o[4]  * inv, o[5]  * inv, o[6]  * inv, o[7]  * inv};
    op[2] = (float4){o[8]  * inv, o[9]  * inv, o[10] * inv, o[11] * inv};
    op[3] = (float4){o[12] * inv, o[13] * inv, o[14] * inv, o[15] * inv};
  }
}

extern "C" void kernel_launch(void* const* d_in, const int* in_sizes, int n_in,
                              void* d_out, int out_size, void* d_ws, size_t ws_size,
                              hipStream_t stream) {
  const float* X  = (const float*)d_in[0];
  const float* Wq = (const float*)d_in[1];
  const float* bq = (const float*)d_in[2];
  const float* Wk = (const float*)d_in[3];
  const float* bk = (const float*)d_in[4];
  const float* Wv = (const float*)d_in[5];
  const float* bv = (const float*)d_in[6];
  const int* winp = (const int*)d_in[7];

  const int M = in_sizes[0] / H_DIM;  // B*T = 16384
  const size_t MH = (size_t)M * H_DIM;
  const size_t HH = (size_t)H_DIM * H_DIM;

  // Workspace (bf16): Xb | Wqb | Wkb | Wvb | Qb | Kb | Vb  (~134 MiB)
  __hip_bfloat16* Xb  = (__hip_bfloat16*)d_ws;
  __hip_bfloat16* Wqb = Xb  + MH;
  __hip_bfloat16* Wkb = Wqb + HH;
  __hip_bfloat16* Wvb = Wkb + HH;
  __hip_bfloat16* Qb  = Wvb + HH;
  __hip_bfloat16* Kb  = Qb  + MH;
  __hip_bfloat16* Vb  = Kb  + MH;
  float* Out = (float*)d_out;

  // 1) f32 -> bf16 conversions.
  cvt_kernel<<<2048, 256, 0, stream>>>(X, Xb, (int)(MH / 8));
  cvt3_kernel<<<dim3(512, 3), 256, 0, stream>>>(Wq, Wk, Wv, Wqb, Wkb, Wvb,
                                                (int)(HH / 8));

  // 2) Fused QKV GEMM — 8-phase 256x256.
  dim3 g1(M / 256, 12);  // 64 x 12 = 768 blocks, 512 threads
  qkv_gemm8_kernel<<<g1, 512, 0, stream>>>(Xb, Wqb, Wkb, Wvb, bq, bk, bv,
                                           Qb, Kb, Vb, M);

  // 3) Windowed attention (r4 per-row version, f32 out).
  const int blocks = M / 4;  // 1 wave per row, 4 waves per 256-thread block
  local_attn_kernel<<<blocks, 256, 0, stream>>>(Qb, Kb, Vb, winp, Out, M);
}

// Round 10
// 290.727 us; speedup vs baseline: 1.5560x; 1.0052x over previous
//
#include <hip/hip_runtime.h>
#include <hip/hip_bf16.h>
#include <stdint.h>
#include <math.h>

typedef __attribute__((ext_vector_type(8))) short short8;
typedef __attribute__((ext_vector_type(4))) float f32x4;

#define H_DIM 1024
#define T_SEQ 4096

static __device__ __forceinline__ float bf2f(unsigned short u) {
  union { unsigned int i; float f; } c;
  c.i = ((unsigned int)u) << 16;
  return c.f;
}

static __device__ __forceinline__ unsigned short f2bf(float f) {
  __hip_bfloat16 h = __float2bfloat16(f);  // RNE
  unsigned short u;
  __builtin_memcpy(&u, &h, 2);
  return u;
}

static __device__ __forceinline__ void gload16(const void* g, void* l) {
  __builtin_amdgcn_global_load_lds(
      (const __attribute__((address_space(1))) void*)g,
      (__attribute__((address_space(3))) void*)l,
      16, 0, 0);
}

#define FENCE asm volatile("" ::: "memory")
#define BAR   __builtin_amdgcn_s_barrier()

// ---------------------------------------------------------------------------
// f32 -> bf16 conversion kernels (unchanged; ~29 us total).
// ---------------------------------------------------------------------------
__global__ __launch_bounds__(256) void cvt_kernel(
    const float* __restrict__ in, __hip_bfloat16* __restrict__ out, int n8)
{
  int i = blockIdx.x * blockDim.x + threadIdx.x;
  const int stride = gridDim.x * blockDim.x;
  for (; i < n8; i += stride) {
    const float4* p = (const float4*)in + (size_t)i * 2;
    float4 a = p[0], b = p[1];
    short8 o;
    o[0] = (short)f2bf(a.x); o[1] = (short)f2bf(a.y);
    o[2] = (short)f2bf(a.z); o[3] = (short)f2bf(a.w);
    o[4] = (short)f2bf(b.x); o[5] = (short)f2bf(b.y);
    o[6] = (short)f2bf(b.z); o[7] = (short)f2bf(b.w);
    ((short8*)out)[i] = o;
  }
}

__global__ __launch_bounds__(256) void cvt3_kernel(
    const float* __restrict__ i0, const float* __restrict__ i1,
    const float* __restrict__ i2,
    __hip_bfloat16* __restrict__ o0, __hip_bfloat16* __restrict__ o1,
    __hip_bfloat16* __restrict__ o2, int n8)
{
  const float* in = (blockIdx.y == 0) ? i0 : ((blockIdx.y == 1) ? i1 : i2);
  __hip_bfloat16* out = (blockIdx.y == 0) ? o0 : ((blockIdx.y == 1) ? o1 : o2);
  int i = blockIdx.x * blockDim.x + threadIdx.x;
  const int stride = gridDim.x * blockDim.x;
  for (; i < n8; i += stride) {
    const float4* p = (const float4*)in + (size_t)i * 2;
    float4 a = p[0], b = p[1];
    short8 o;
    o[0] = (short)f2bf(a.x); o[1] = (short)f2bf(a.y);
    o[2] = (short)f2bf(a.z); o[3] = (short)f2bf(a.w);
    o[4] = (short)f2bf(b.x); o[5] = (short)f2bf(b.y);
    o[6] = (short)f2bf(b.z); o[7] = (short)f2bf(b.w);
    ((short8*)out)[i] = o;
  }
}

// ---------------------------------------------------------------------------
// 8-phase 256x256 fused QKV GEMM (T2 swizzle + T3/T4 counted-vmcnt + T5).
// r8 measured: 110 us, MfmaUtil 39.6%, bank-conflict 0.
// r9 change: REMOVED per-phase `s_waitcnt lgkmcnt(0)` + `sched_barrier(0)`.
// The ds_reads are compiler-generated loads with tracked deps — hipcc emits
// fine-grained per-register lgkmcnt before each consuming MFMA, so early
// MFMAs overlap the LDS drain of later reads (m97 asm evidence; m141 showed
// order-pinning regresses ~40%). Safety: every read is consumed before its
// phase's closing barrier; regions re-staged >=2 phases after last read;
// FENCE + volatile vmcnt asm block compiler motion across stage/wait points.
// ---------------------------------------------------------------------------
#define GNT 16          // K tiles = 1024/64

static __device__ __forceinline__ void stage_half(
    const __hip_bfloat16* __restrict__ G, int grow0, int k0, char* dstHalf,
    int tid)
{
  const int w = tid >> 6, l = tid & 63;
  #pragma unroll
  for (int r = 0; r < 2; ++r) {
    const int D = (r * 8 + w) * 1024 + l * 16;     // linear LDS byte in half
    const int L = D ^ (((D >> 7) & 7) << 4);       // inverse-swizzled source
    const int row = L >> 7;                        // 0..127
    const int cb  = L & 127;                       // byte within 128B row
    const char* src = (const char*)G + (size_t)(grow0 + row) * (H_DIM * 2)
                      + k0 * 2 + cb;
    gload16(src, dstHalf + D);
  }
}

static __device__ __forceinline__ short8 lds_frag(const char* half, int row,
                                                  int ksub, int kq)
{
  int a = row * 128 + ksub * 64 + kq * 16;
  a ^= ((row & 7) << 4);   // same involution ((a>>7)&7 == row&7)
  return *(const short8*)(half + a);
}

__global__ __launch_bounds__(512, 1) void qkv_gemm8_kernel(
    const __hip_bfloat16* __restrict__ X,
    const __hip_bfloat16* __restrict__ Wq,
    const __hip_bfloat16* __restrict__ Wk,
    const __hip_bfloat16* __restrict__ Wv,
    const float* __restrict__ bq,
    const float* __restrict__ bk,
    const float* __restrict__ bv,
    __hip_bfloat16* __restrict__ Qo,
    __hip_bfloat16* __restrict__ Ko,
    __hip_bfloat16* __restrict__ Vo,
    int M)
{
  __shared__ char lds[131072];   // 2 bufs x (A 32KB + B 32KB)

  const int m0 = blockIdx.x * 256;
  const int ytile = blockIdx.y;          // 0..11
  const int which = ytile >> 2;          // 0:Q 1:K 2:V
  const int nb = (ytile & 3) * 256;      // col base within selected W

  const __hip_bfloat16* Wsel = (which == 0) ? Wq : ((which == 1) ? Wk : Wv);
  const float* Bsel          = (which == 0) ? bq : ((which == 1) ? bk : bv);
  __hip_bfloat16* Osel       = (which == 0) ? Qo : ((which == 1) ? Ko : Vo);

  const int tid  = threadIdx.x;
  const int lane = tid & 63;
  const int wid  = tid >> 6;       // 0..7
  const int wr   = wid >> 2;       // 0..1  (M dim, 128 rows each)
  const int wc   = wid & 3;        // 0..3  (N dim, 64 cols each)
  const int lrow = lane & 15;
  const int kq   = lane >> 4;

  // LDS regions: buf b in [b*65536, +65536): A halves at 0,16K; B at 32K,48K.
  #define AHALF(b, h) (lds + (b) * 65536 + (h) * 16384)
  #define BHALF(b, h) (lds + (b) * 65536 + 32768 + (h) * 16384)

  f32x4 acc[8][4];
  #pragma unroll
  for (int i = 0; i < 8; ++i)
    #pragma unroll
    for (int j = 0; j < 4; ++j)
      acc[i][j] = (f32x4){0.f, 0.f, 0.f, 0.f};

  // ---- Prologue: stage tile0 fully + tile1's B halves; vmcnt(4); barrier.
  stage_half(Wsel, nb +   0, 0,  BHALF(0, 0), tid);
  stage_half(Wsel, nb + 128, 0,  BHALF(0, 1), tid);
  stage_half(X,    m0 +   0, 0,  AHALF(0, 0), tid);
  stage_half(X,    m0 + 128, 0,  AHALF(0, 1), tid);
  stage_half(Wsel, nb +   0, 64, BHALF(1, 0), tid);
  stage_half(Wsel, nb + 128, 64, BHALF(1, 1), tid);
  asm volatile("s_waitcnt vmcnt(4)" ::: "memory");
  BAR;

  short8 aF[4][2];
  short8 bF[4][2];

  for (int t = 0; t < GNT; ++t) {
    const int cur = t & 1, nxt = cur ^ 1;
    const char* myA = AHALF(cur, wr);
    const char* myB = BHALF(cur, wc >> 1);
    const int rB0 = (wc & 1) * 64;

    // ---------------- phase 0: read A[m0-3], B[n0-1]; stage A0[t+1]
    #pragma unroll
    for (int mi = 0; mi < 4; ++mi)
      #pragma unroll
      for (int ks = 0; ks < 2; ++ks)
        aF[mi][ks] = lds_frag(myA, mi * 16 + lrow, ks, kq);
    #pragma unroll
    for (int ni = 0; ni < 2; ++ni)
      #pragma unroll
      for (int ks = 0; ks < 2; ++ks)
        bF[ni][ks] = lds_frag(myB, rB0 + ni * 16 + lrow, ks, kq);
    if (t + 1 < GNT) stage_half(X, m0 + 0, (t + 1) * 64, AHALF(nxt, 0), tid);
    FENCE; BAR;
    __builtin_amdgcn_s_setprio(1);
    #pragma unroll
    for (int mi = 0; mi < 4; ++mi)
      #pragma unroll
      for (int ni = 0; ni < 2; ++ni)
        #pragma unroll
        for (int ks = 0; ks < 2; ++ks)
          acc[mi][ni] = __builtin_amdgcn_mfma_f32_16x16x32_bf16(
              aF[mi][ks], bF[ni][ks], acc[mi][ni], 0, 0, 0);
    __builtin_amdgcn_s_setprio(0);
    FENCE; BAR;

    // ---------------- phase 1: read B[n2-3]; stage A1[t+1]
    #pragma unroll
    for (int ni = 2; ni < 4; ++ni)
      #pragma unroll
      for (int ks = 0; ks < 2; ++ks)
        bF[ni][ks] = lds_frag(myB, rB0 + ni * 16 + lrow, ks, kq);
    if (t + 1 < GNT) stage_half(X, m0 + 128, (t + 1) * 64, AHALF(nxt, 1), tid);
    FENCE; BAR;
    __builtin_amdgcn_s_setprio(1);
    #pragma unroll
    for (int mi = 0; mi < 4; ++mi)
      #pragma unroll
      for (int ni = 2; ni < 4; ++ni)
        #pragma unroll
        for (int ks = 0; ks < 2; ++ks)
          acc[mi][ni] = __builtin_amdgcn_mfma_f32_16x16x32_bf16(
              aF[mi][ks], bF[ni][ks], acc[mi][ni], 0, 0, 0);
    __builtin_amdgcn_s_setprio(0);
    FENCE; BAR;

    // ---------------- phase 2: read A[m4-7]; stage B0[t+2]
    #pragma unroll
    for (int mi = 0; mi < 4; ++mi)
      #pragma unroll
      for (int ks = 0; ks < 2; ++ks)
        aF[mi][ks] = lds_frag(myA, (mi + 4) * 16 + lrow, ks, kq);
    if (t + 2 < GNT) stage_half(Wsel, nb + 0, (t + 2) * 64, BHALF(cur, 0), tid);
    FENCE; BAR;
    __builtin_amdgcn_s_setprio(1);
    #pragma unroll
    for (int mi = 0; mi < 4; ++mi)
      #pragma unroll
      for (int ni = 0; ni < 2; ++ni)
        #pragma unroll
        for (int ks = 0; ks < 2; ++ks)
          acc[mi + 4][ni] = __builtin_amdgcn_mfma_f32_16x16x32_bf16(
              aF[mi][ks], bF[ni][ks], acc[mi + 4][ni], 0, 0, 0);
    __builtin_amdgcn_s_setprio(0);
    FENCE; BAR;

    // ---------------- phase 3: stage B1[t+2]; MFMA from regs; tile-end vmcnt
    if (t + 2 < GNT) stage_half(Wsel, nb + 128, (t + 2) * 64, BHALF(cur, 1), tid);
    FENCE;
    __builtin_amdgcn_s_setprio(1);
    #pragma unroll
    for (int mi = 0; mi < 4; ++mi)
      #pragma unroll
      for (int ni = 2; ni < 4; ++ni)
        #pragma unroll
        for (int ks = 0; ks < 2; ++ks)
          acc[mi + 4][ni] = __builtin_amdgcn_mfma_f32_16x16x32_bf16(
              aF[mi][ks], bF[ni][ks], acc[mi + 4][ni], 0, 0, 0);
    __builtin_amdgcn_s_setprio(0);
    // End-of-tile: ensure tile t+1's 4 halves have landed before anyone reads.
    if (t + 2 < GNT) { asm volatile("s_waitcnt vmcnt(4)" ::: "memory"); }
    else             { asm volatile("s_waitcnt vmcnt(0)" ::: "memory"); }
    FENCE; BAR;
  }

  // ---- Epilogue: bias + bf16 store. C/D: col=lane&15, row=(lane>>4)*4+reg.
  #pragma unroll
  for (int ni = 0; ni < 4; ++ni) {
    const int col = nb + wc * 64 + ni * 16 + lrow;
    const float bias = Bsel[col];
    #pragma unroll
    for (int mi = 0; mi < 8; ++mi) {
      const int rowbase = m0 + wr * 128 + mi * 16 + kq * 4;
      #pragma unroll
      for (int r = 0; r < 4; ++r) {
        float v = acc[mi][ni][r] + bias;
        Osel[(size_t)(rowbase + r) * H_DIM + col] = __float2bfloat16(v);
      }
    }
  }
  #undef AHALF
  #undef BHALF
}

// ---------------------------------------------------------------------------
// Windowed causal attention (r4-verified, ~64 us). One wave per row.
// ---------------------------------------------------------------------------
__global__ __launch_bounds__(256) void local_attn_kernel(
    const __hip_bfloat16* __restrict__ Q,
    const __hip_bfloat16* __restrict__ Km,
    const __hip_bfloat16* __restrict__ V,
    const int* __restrict__ winp,
    float* __restrict__ Out,
    int M)
{
  const int row = (int)((blockIdx.x * blockDim.x + threadIdx.x) >> 6);
  if (row >= M) return;
  const int lane = threadIdx.x & 63;
  const int t = row & (T_SEQ - 1);
  const int Wn = *winp;  // 8 for this problem
  const float scale = 0.03125f;  // 1/sqrt(1024)

  const size_t base = (size_t)row * H_DIM + (size_t)lane * 16;

  float q[16];
  {
    const short8* p = (const short8*)(Q + base);
    short8 a = p[0], b = p[1];
    #pragma unroll
    for (int j = 0; j < 8; ++j) {
      q[j]     = bf2f((unsigned short)a[j]);
      q[8 + j] = bf2f((unsigned short)b[j]);
    }
  }

  if (Wn == 8) {
    float sc[9];
    #pragma unroll
    for (int w = 0; w < 9; ++w) {
      const int dt = 8 - w;
      float s = -INFINITY;
      if (t - dt >= 0) {
        const short8* kp = (const short8*)(Km + base - (size_t)dt * H_DIM);
        short8 ka = kp[0], kb = kp[1];
        float d = 0.f;
        #pragma unroll
        for (int j = 0; j < 8; ++j) {
          d += q[j]     * bf2f((unsigned short)ka[j]);
          d += q[8 + j] * bf2f((unsigned short)kb[j]);
        }
        #pragma unroll
        for (int off = 32; off >= 1; off >>= 1) d += __shfl_xor(d, off, 64);
        s = d * scale;
      }
      sc[w] = s;
    }
    float m = sc[0];
    #pragma unroll
    for (int w = 1; w < 9; ++w) m = fmaxf(m, sc[w]);
    float l = 0.f;
    #pragma unroll
    for (int w = 0; w < 9; ++w) { sc[w] = __expf(sc[w] - m); l += sc[w]; }
    const float inv = 1.f / l;

    float o[16];
    #pragma unroll
    for (int j = 0; j < 16; ++j) o[j] = 0.f;
    #pragma unroll
    for (int w = 0; w < 9; ++w) {
      const int dt = 8 - w;
      if (t - dt >= 0) {
        const short8* vp = (const short8*)(V + base - (size_t)dt * H_DIM);
        short8 va = vp[0], vb = vp[1];
        const float aw = sc[w] * inv;
        #pragma unroll
        for (int j = 0; j < 8; ++j) {
          o[j]     += aw * bf2f((unsigned short)va[j]);
          o[8 + j] += aw * bf2f((unsigned short)vb[j]);
        }
      }
    }

    float4* op = (float4*)(Out + base);
    op[0] = (float4){o[0],  o[1],  o[2],  o[3]};
    op[1] = (float4){o[4],  o[5],  o[6],  o[7]};
    op[2] = (float4){o[8],  o[9],  o[10], o[11]};
    op[3] = (float4){o[12], o[13], o[14], o[15]};
  } else {
    float m = -INFINITY, l = 0.f;
    float o[16];
    #pragma unroll
    for (int j = 0; j < 16; ++j) o[j] = 0.f;
    for (int w = 0; w <= Wn; ++w) {
      const int dt = Wn - w;
      if (t - dt < 0) continue;
      const short8* kp = (const short8*)(Km + base - (size_t)dt * H_DIM);
      short8 ka = kp[0], kb = kp[1];
      float d = 0.f;
      #pragma unroll
      for (int j = 0; j < 8; ++j) {
        d += q[j]     * bf2f((unsigned short)ka[j]);
        d += q[8 + j] * bf2f((unsigned short)kb[j]);
      }
      #pragma unroll
      for (int off = 32; off >= 1; off >>= 1) d += __shfl_xor(d, off, 64);
      const float s = d * scale;
      const float mn = fmaxf(m, s);
      const float corr = (m == -INFINITY) ? 0.f : __expf(m - mn);
      const float p = __expf(s - mn);
      l = l * corr + p;
      const short8* vp = (const short8*)(V + base - (size_t)dt * H_DIM);
      short8 va = vp[0], vb = vp[1];
      #pragma unroll
      for (int j = 0; j < 8; ++j) {
        o[j]     = o[j]     * corr + p * bf2f((unsigned short)va[j]);
        o[8 + j] = o[8 + j] * corr + p * bf2f((unsigned short)vb[j]);
      }
      m = mn;
    }
    const float inv = 1.f / l;
    float4* op = (float4*)(Out + base);
    op[0] = (float4){o[0]  * inv, o[1]  * inv, o[2]  * inv, o[3]  * inv};
    op[1] = (float4){o[4]  * inv, o[5]  * inv, o[6]  * inv, o[7]  * inv};
    op[2] = (float4){o[8]  * inv, o[9]  * inv, o[10] * inv, o[11] * inv};
    op[3] = (float4){o[12] * inv, o[13] * inv, o[14] * inv, o[15] * inv};
  }
}

extern "C" void kernel_launch(void* const* d_in, const int* in_sizes, int n_in,
                              void* d_out, int out_size, void* d_ws, size_t ws_size,
                              hipStream_t stream) {
  const float* X  = (const float*)d_in[0];
  const float* Wq = (const float*)d_in[1];
  const float* bq = (const float*)d_in[2];
  const float* Wk = (const float*)d_in[3];
  const float* bk = (const float*)d_in[4];
  const float* Wv = (const float*)d_in[5];
  const float* bv = (const float*)d_in[6];
  const int* winp = (const int*)d_in[7];

  const int M = in_sizes[0] / H_DIM;  // B*T = 16384
  const size_t MH = (size_t)M * H_DIM;
  const size_t HH = (size_t)H_DIM * H_DIM;

  // Workspace (bf16): Xb | Wqb | Wkb | Wvb | Qb | Kb | Vb  (~134 MiB)
  __hip_bfloat16* Xb  = (__hip_bfloat16*)d_ws;
  __hip_bfloat16* Wqb = Xb  + MH;
  __hip_bfloat16* Wkb = Wqb + HH;
  __hip_bfloat16* Wvb = Wkb + HH;
  __hip_bfloat16* Qb  = Wvb + HH;
  __hip_bfloat16* Kb  = Qb  + MH;
  __hip_bfloat16* Vb  = Kb  + MH;
  float* Out = (float*)d_out;

  // 1) f32 -> bf16 conversions.
  cvt_kernel<<<2048, 256, 0, stream>>>(X, Xb, (int)(MH / 8));
  cvt3_kernel<<<dim3(512, 3), 256, 0, stream>>>(Wq, Wk, Wv, Wqb, Wkb, Wvb,
                                                (int)(HH / 8));

  // 2) Fused QKV GEMM — 8-phase 256x256.
  dim3 g1(M / 256, 12);  // 64 x 12 = 768 blocks, 512 threads
  qkv_gemm8_kernel<<<g1, 512, 0, stream>>>(Xb, Wqb, Wkb, Wvb, bq, bk, bv,
                                           Qb, Kb, Vb, M);

  // 3) Windowed attention (r4 per-row version, f32 out).
  const int blocks = M / 4;  // 1 wave per row, 4 waves per 256-thread block
  local_attn_kernel<<<blocks, 256, 0, stream>>>(Qb, Kb, Vb, winp, Out, M);
}